// Round 5
// baseline (52.939 us; speedup 1.0000x reference)
//
#include <hip/hip_runtime.h>
#include <stdint.h>

#define B_ 128
#define S_ 512
#define H_ 1024
#define L_ 9
#define CH 128            // floats of h per chunk
#define NCH (H_ / CH)     // 8 chunks
#define ROWS 64           // output rows per block

typedef __attribute__((address_space(3))) uint8_t lds8_t;
typedef __attribute__((address_space(1))) uint8_t glob8_t;

__device__ __forceinline__ void bias_softmax(const float* __restrict__ bias,
                                             float* pv) {
    float mx = bias[0];
#pragma unroll
    for (int l = 1; l < L_; ++l) mx = fmaxf(mx, bias[l]);
    float s = 0.f;
#pragma unroll
    for (int l = 0; l < L_; ++l) { pv[l] = expf(bias[l] - mx); s += pv[l]; }
    float inv = 1.f / s;
#pragma unroll
    for (int l = 0; l < L_; ++l) pv[l] *= inv;
}

// ---- Kernel A: per-batch stable-compaction scan (map only) ----
__global__ __launch_bounds__(64) void prep_kernel(
    const int* __restrict__ valid, int* __restrict__ ws_src,
    int* __restrict__ ws_nv) {
    const int lane = threadIdx.x;
    const int b = blockIdx.x;
    const int* vrow = valid + (size_t)b * S_;
    int base = 0;
#pragma unroll
    for (int c = 0; c < 8; ++c) {
        int vv = vrow[c * 64 + lane];
        unsigned long long m = __ballot(vv != 0);
        if (vv) {
            int pre = __popcll(m & ((1ull << lane) - 1ull));
            ws_src[b * S_ + base + pre] = c * 64 + lane;
        }
        base += __popcll(m);
    }
    if (lane == 0) ws_nv[b] = base;
}

// ---- Kernel B: dense rows, coalesced LDS staging, scalar-path W ----
// Block: 256 thr (4 waves), 64 dense output rows. Wave w stages rows
// [16w,16w+16) via global_load_lds (1KB/instr = two contiguous 512B row
// segments); computes c4-slice [8w,8w+8) of all 64 rows (lane = row).
// Swizzle: global source column c4^=(row&31); same XOR on ds_read side.
__global__ __launch_bounds__(256, 2) void gemm_kernel(
    const float* __restrict__ seq, const float* __restrict__ W,
    const float* __restrict__ bias, const int* __restrict__ ws_src,
    const int* __restrict__ ws_nv, float* __restrict__ out) {
    __shared__ __align__(16) float tile[2][ROWS][CH];  // 64 KB double buffer
    __shared__ int offs[B_ + 1];
    __shared__ int srcrow[ROWS];  // absolute seq row per block-row

    const int lane = threadIdx.x & 63;
    const int wv = __builtin_amdgcn_readfirstlane(threadIdx.x >> 6);

    // 128-wide exclusive prefix of ws_nv -> offs[0..128] (wave 0)
    if (threadIdx.x < 64) {
        int s0 = ws_nv[lane];
        int s1 = ws_nv[64 + lane];
#pragma unroll
        for (int d = 1; d < 64; d <<= 1) {
            int t0 = __shfl_up(s0, d, 64);
            int t1 = __shfl_up(s1, d, 64);
            if (lane >= d) { s0 += t0; s1 += t1; }
        }
        int tot0 = __shfl(s0, 63, 64);
        offs[1 + lane] = s0;
        offs[65 + lane] = tot0 + s1;
        if (lane == 0) offs[0] = 0;
    }
    __syncthreads();

    const int total = offs[B_];
    const int G0 = blockIdx.x * ROWS;
    const int G = G0 + lane;

    // ---- per-lane output mapping: G -> (orow, srcabs, isPad) ----
    int orow, srcabs;
    bool isPad;
    if (G < total) {  // dense valid row: search offs
        isPad = false;
        int lo = 0, hi = B_;
        while (hi - lo > 1) {
            int mid = (lo + hi) >> 1;
            if (offs[mid] <= G) lo = mid; else hi = mid;
        }
        int j = G - offs[lo];
        orow = lo * S_ + j;
        srcabs = lo * S_ + ws_src[orow];
    } else {  // pad row: search padoff[x] = x*S - offs[x]
        isPad = true;
        int P = G - total;
        int lo = 0, hi = B_;
        while (hi - lo > 1) {
            int mid = (lo + hi) >> 1;
            if (mid * S_ - offs[mid] <= P) lo = mid; else hi = mid;
        }
        int nv = offs[lo + 1] - offs[lo];
        int j = nv + (P - (lo * S_ - offs[lo]));
        orow = lo * S_ + j;
        srcabs = 0;  // dummy (row 0): staged but result overridden
    }

    // ---- all-pad block: write softmax(bias), no staging reads ----
    if (G0 >= total) {
        if (threadIdx.x < 64) {
            float pv[L_];
            bias_softmax(bias, pv);
            float* op = out + (size_t)orow * L_;
#pragma unroll
            for (int l = 0; l < L_; ++l) op[l] = pv[l];
        }
        return;
    }

    if (threadIdx.x < 64) srcrow[lane] = srcabs;
    __syncthreads();

    // ---- staging addresses (chunk 0): instr i covers rows 16w+2i,+1 ----
    const int rhalf = lane >> 5;
    const int c4l = lane & 31;
    const float* gbase[8];
#pragma unroll
    for (int i = 0; i < 8; ++i) {
        int row = 16 * wv + 2 * i + rhalf;
        int csrc = c4l ^ (row & 31);  // pre-swizzled global column
        gbase[i] = seq + (size_t)srcrow[row] * H_ + csrc * 4;
    }

    // ---- per-lane swizzled LDS read offsets (lane = row), bytes ----
    int ldsoff[8];
#pragma unroll
    for (int c = 0; c < 8; ++c) {
        int c4r = (8 * wv + c) ^ (lane & 31);
        ldsoff[c] = lane * (CH * 4) + c4r * 16;
    }

    auto stage = [&](int buf, int ch) {
#pragma unroll
        for (int i = 0; i < 8; ++i) {
            __builtin_amdgcn_global_load_lds(
                (const glob8_t*)(gbase[i] + ch * CH),
                (lds8_t*)&tile[buf][16 * wv + 2 * i][0], 16, 0, 0);
        }
    };

    float acc[L_];
#pragma unroll
    for (int l = 0; l < L_; ++l) acc[l] = 0.f;

    stage(0, 0);
    __syncthreads();  // drains vmcnt(0): buf0 ready

#pragma unroll
    for (int ch = 0; ch < NCH; ++ch) {
        const int buf = ch & 1;
        if (ch + 1 < NCH) stage(buf ^ 1, ch + 1);  // prefetch next chunk
        const char* tb = (const char*)&tile[buf][0][0];
#pragma unroll
        for (int c = 0; c < 8; ++c) {
            float4 xv = *(const float4*)(tb + ldsoff[c]);
            const int h = ch * CH + (8 * wv + c) * 4;
            const float* wr = W + (size_t)h * L_;  // wave-uniform -> s_load
            float xk[4] = {xv.x, xv.y, xv.z, xv.w};
#pragma unroll
            for (int k = 0; k < 4; ++k)
#pragma unroll
                for (int l = 0; l < L_; ++l)
                    acc[l] = fmaf(xk[k], wr[k * L_ + l], acc[l]);
        }
        __syncthreads();  // drains vmcnt: next buf staged, this buf free
    }

    // ---- cross-wave reduce (overlay on tile), softmax, store ----
    float* red = &tile[0][0][0];  // [4][64][9] floats, 9.2 KB < 32 KB
#pragma unroll
    for (int l = 0; l < L_; ++l) red[(wv * 64 + lane) * L_ + l] = acc[l];
    __syncthreads();

    if (threadIdx.x < 64) {
        float* op = out + (size_t)orow * L_;
        if (isPad) {
            float pv[L_];
            bias_softmax(bias, pv);
#pragma unroll
            for (int l = 0; l < L_; ++l) op[l] = pv[l];
        } else {
            float v[L_];
#pragma unroll
            for (int l = 0; l < L_; ++l)
                v[l] = red[lane * L_ + l] + red[(64 + lane) * L_ + l] +
                       red[(128 + lane) * L_ + l] + red[(192 + lane) * L_ + l] +
                       bias[l];
            float mx = v[0];
#pragma unroll
            for (int l = 1; l < L_; ++l) mx = fmaxf(mx, v[l]);
            float s = 0.f;
#pragma unroll
            for (int l = 0; l < L_; ++l) {
                v[l] = expf(v[l] - mx);
                s += v[l];
            }
            float inv = 1.f / s;
#pragma unroll
            for (int l = 0; l < L_; ++l) op[l] = v[l] * inv;
        }
    }
}

extern "C" void kernel_launch(void* const* d_in, const int* in_sizes, int n_in,
                              void* d_out, int out_size, void* d_ws, size_t ws_size,
                              hipStream_t stream) {
    const float* seq = (const float*)d_in[0];   // [B,S,H] f32
    const float* W = (const float*)d_in[1];     // [H,L] f32
    const float* bias = (const float*)d_in[2];  // [L] f32
    const int* valid = (const int*)d_in[3];     // [B,S] i32
    float* out = (float*)d_out;                 // [B,S,L] f32

    int* ws_src = (int*)d_ws;        // [128*512] within-batch source indices
    int* ws_nv = ws_src + B_ * S_;   // [128] valid counts

    prep_kernel<<<dim3(B_), dim3(64), 0, stream>>>(valid, ws_src, ws_nv);
    gemm_kernel<<<dim3(B_ * S_ / ROWS), dim3(256), 0, stream>>>(seq, W, bias,
                                                                ws_src, ws_nv, out);
}

// Round 6
// 35.808 us; speedup vs baseline: 1.4784x; 1.4784x over previous
//
#include <hip/hip_runtime.h>

#define B_ 128
#define S_ 512
#define H_ 1024
#define L_ 9
#define RPB 64  // rows per block (16 per wave)

// ---- Kernel A: per-batch stable-compaction scan (map only) ----
__global__ __launch_bounds__(64) void prep_kernel(
    const int* __restrict__ valid, int* __restrict__ ws_src,
    int* __restrict__ ws_nv) {
    const int lane = threadIdx.x;
    const int b = blockIdx.x;
    const int* vrow = valid + (size_t)b * S_;
    int base = 0;
#pragma unroll
    for (int c = 0; c < 8; ++c) {
        int vv = vrow[c * 64 + lane];
        unsigned long long m = __ballot(vv != 0);
        if (vv) {
            int pre = __popcll(m & ((1ull << lane) - 1ull));
            ws_src[b * S_ + base + pre] = c * 64 + lane;
        }
        base += __popcll(m);
    }
    if (lane == 0) ws_nv[b] = base;
}

__device__ __forceinline__ void bias_softmax_store(const float* __restrict__ bias,
                                                   float* __restrict__ op) {
    float pv[L_];
    float mx = bias[0];
#pragma unroll
    for (int l = 1; l < L_; ++l) mx = fmaxf(mx, bias[l]);
    float s = 0.f;
#pragma unroll
    for (int l = 0; l < L_; ++l) { pv[l] = expf(bias[l] - mx); s += pv[l]; }
    float inv = 1.f / s;
#pragma unroll
    for (int l = 0; l < L_; ++l) op[l] = pv[l] * inv;
}

// ---- Kernel B: coalesced 256B-run streaming, W in LDS, no loop barriers ----
// Block 256 thr (4 waves), 64 dense rows. Lane split: hl=lane&15 spans h
// (16 lanes x float4 = 256B contiguous per row per instr), g=lane>>4 picks the
// row; each lane carries 4 row-slots s -> 16 rows/wave. W (36KB) loaded to LDS
// once; per-iteration 9x ds_read_b128, 16 distinct addrs, 4-lane broadcast,
// 2-way bank alias = conflict-free. 16-lane shfl_xor butterfly reduces h.
__global__ __launch_bounds__(256, 4) void gemm_kernel(
    const float* __restrict__ seq, const float* __restrict__ W,
    const float* __restrict__ bias, const int* __restrict__ ws_src,
    const int* __restrict__ ws_nv, float* __restrict__ out) {
    __shared__ __align__(16) float Wl[H_ * L_];  // 36,864 B
    __shared__ int offs[B_ + 1];
    __shared__ int srow[RPB];    // absolute source row, -1 = pad
    __shared__ int orow_s[RPB];  // absolute output row

    const int lane = threadIdx.x & 63;
    const int wv = __builtin_amdgcn_readfirstlane(threadIdx.x >> 6);

    // 128-wide exclusive prefix of ws_nv -> offs[0..128] (wave 0)
    if (threadIdx.x < 64) {
        int s0 = ws_nv[lane];
        int s1 = ws_nv[64 + lane];
#pragma unroll
        for (int d = 1; d < 64; d <<= 1) {
            int t0 = __shfl_up(s0, d, 64);
            int t1 = __shfl_up(s1, d, 64);
            if (lane >= d) { s0 += t0; s1 += t1; }
        }
        int tot0 = __shfl(s0, 63, 64);
        offs[1 + lane] = s0;
        offs[65 + lane] = tot0 + s1;
        if (lane == 0) offs[0] = 0;
    }
    __syncthreads();

    const int total = offs[B_];
    const int G0 = blockIdx.x * RPB;
    const bool anyValid = G0 < total;  // block-uniform

    // ---- mapping for this block's 64 rows (thread t -> row t) ----
    if (threadIdx.x < RPB) {
        const int G = G0 + threadIdx.x;
        int orow, srcabs;
        if (G < total) {
            int lo = 0, hi = B_;
            while (hi - lo > 1) {
                int mid = (lo + hi) >> 1;
                if (offs[mid] <= G) lo = mid; else hi = mid;
            }
            int j = G - offs[lo];
            orow = lo * S_ + j;
            srcabs = lo * S_ + ws_src[orow];
        } else {
            int P = G - total;
            int lo = 0, hi = B_;
            while (hi - lo > 1) {
                int mid = (lo + hi) >> 1;
                if (mid * S_ - offs[mid] <= P) lo = mid; else hi = mid;
            }
            int nv = offs[lo + 1] - offs[lo];
            int j = nv + (P - (lo * S_ - offs[lo]));
            orow = lo * S_ + j;
            srcabs = -1;
        }
        srow[threadIdx.x] = srcabs;
        orow_s[threadIdx.x] = orow;
    }

    // ---- cooperative W -> LDS (skip for all-pad blocks) ----
    if (anyValid) {
        const float4* Wg = (const float4*)W;
        float4* Wd = (float4*)Wl;
#pragma unroll
        for (int k = 0; k < 9; ++k)  // 2304 float4s = 9 * 256
            Wd[k * 256 + threadIdx.x] = Wg[k * 256 + threadIdx.x];
    }
    __syncthreads();

    if (!anyValid) {  // all-pad block: bias softmax only, no W/seq reads
        if (threadIdx.x < RPB)
            bias_softmax_store(bias, out + (size_t)orow_s[threadIdx.x] * L_);
        return;
    }

    const int hl = lane & 15;
    const int g = lane >> 4;

    // this lane's 4 source rows (pad -> clamp to row 0, result overridden)
    const float* xb[4];
#pragma unroll
    for (int s = 0; s < 4; ++s) {
        int rw = 16 * wv + 4 * s + g;
        int sa = srow[rw];
        xb[s] = seq + (size_t)(sa < 0 ? 0 : sa) * H_ + 4 * hl;
    }

    float acc[4][L_];
#pragma unroll
    for (int s = 0; s < 4; ++s)
#pragma unroll
        for (int l = 0; l < L_; ++l) acc[s][l] = 0.f;

    // main loop: 16 its cover h=1024; per it: 4x coalesced float4 (256B runs),
    // 9x broadcast ds_read_b128 of W, 144 FMA. No barriers.
#pragma unroll 2
    for (int it = 0; it < 16; ++it) {
        float4 xv0 = *(const float4*)(xb[0] + 64 * it);
        float4 xv1 = *(const float4*)(xb[1] + 64 * it);
        float4 xv2 = *(const float4*)(xb[2] + 64 * it);
        float4 xv3 = *(const float4*)(xb[3] + 64 * it);
        const float* wf = Wl + 36 * hl + 576 * it;
        float wr[36];
#pragma unroll
        for (int j = 0; j < 9; ++j)
            *(float4*)&wr[4 * j] = *(const float4*)(wf + 4 * j);
        float xk0[4] = {xv0.x, xv0.y, xv0.z, xv0.w};
        float xk1[4] = {xv1.x, xv1.y, xv1.z, xv1.w};
        float xk2[4] = {xv2.x, xv2.y, xv2.z, xv2.w};
        float xk3[4] = {xv3.x, xv3.y, xv3.z, xv3.w};
#pragma unroll
        for (int k = 0; k < 4; ++k)
#pragma unroll
            for (int l = 0; l < L_; ++l) {
                float w = wr[9 * k + l];
                acc[0][l] = fmaf(xk0[k], w, acc[0][l]);
                acc[1][l] = fmaf(xk1[k], w, acc[1][l]);
                acc[2][l] = fmaf(xk2[k], w, acc[2][l]);
                acc[3][l] = fmaf(xk3[k], w, acc[3][l]);
            }
    }

    // ---- butterfly reduce over the 16 h-lanes (register-only) ----
#pragma unroll
    for (int m = 1; m < 16; m <<= 1)
#pragma unroll
        for (int s = 0; s < 4; ++s)
#pragma unroll
            for (int l = 0; l < L_; ++l)
                acc[s][l] += __shfl_xor(acc[s][l], m, 16);

    // ---- write: lane with hl<4 writes row 16*wv + 4*hl + g ----
    if (hl < 4) {
        float v[L_];
#pragma unroll
        for (int s = 0; s < 4; ++s)  // static-index select acc[hl]
            if (hl == s) {
#pragma unroll
                for (int l = 0; l < L_; ++l) v[l] = acc[s][l];
            }
        int rw = 16 * wv + 4 * hl + g;
        float* op = out + (size_t)orow_s[rw] * L_;
        if (srow[rw] < 0) {
            bias_softmax_store(bias, op);
        } else {
#pragma unroll
            for (int l = 0; l < L_; ++l) v[l] += bias[l];
            float mx = v[0];
#pragma unroll
            for (int l = 1; l < L_; ++l) mx = fmaxf(mx, v[l]);
            float s = 0.f;
#pragma unroll
            for (int l = 0; l < L_; ++l) {
                v[l] = expf(v[l] - mx);
                s += v[l];
            }
            float inv = 1.f / s;
#pragma unroll
            for (int l = 0; l < L_; ++l) op[l] = v[l] * inv;
        }
    }
}

extern "C" void kernel_launch(void* const* d_in, const int* in_sizes, int n_in,
                              void* d_out, int out_size, void* d_ws, size_t ws_size,
                              hipStream_t stream) {
    const float* seq = (const float*)d_in[0];   // [B,S,H] f32
    const float* W = (const float*)d_in[1];     // [H,L] f32
    const float* bias = (const float*)d_in[2];  // [L] f32
    const int* valid = (const int*)d_in[3];     // [B,S] i32
    float* out = (float*)d_out;                 // [B,S,L] f32

    int* ws_src = (int*)d_ws;        // [128*512] within-batch source indices
    int* ws_nv = ws_src + B_ * S_;   // [128] valid counts

    prep_kernel<<<dim3(B_), dim3(64), 0, stream>>>(valid, ws_src, ws_nv);
    gemm_kernel<<<dim3(B_ * S_ / RPB), dim3(256), 0, stream>>>(seq, W, bias,
                                                               ws_src, ws_nv, out);
}

// Round 7
// 35.736 us; speedup vs baseline: 1.4814x; 1.0020x over previous
//
#include <hip/hip_runtime.h>

#define B_ 128
#define S_ 512
#define H_ 1024
#define L_ 9
#define RPB 64  // rows per block (16 per wave)

// ---- Kernel A: per-batch stable-compaction scan (map only) ----
__global__ __launch_bounds__(64) void prep_kernel(
    const int* __restrict__ valid, int* __restrict__ ws_src,
    int* __restrict__ ws_nv) {
    const int lane = threadIdx.x;
    const int b = blockIdx.x;
    const int* vrow = valid + (size_t)b * S_;
    int base = 0;
#pragma unroll
    for (int c = 0; c < 8; ++c) {
        int vv = vrow[c * 64 + lane];
        unsigned long long m = __ballot(vv != 0);
        if (vv) {
            int pre = __popcll(m & ((1ull << lane) - 1ull));
            ws_src[b * S_ + base + pre] = c * 64 + lane;
        }
        base += __popcll(m);
    }
    if (lane == 0) ws_nv[b] = base;
}

__device__ __forceinline__ void bias_softmax_store(const float* __restrict__ bias,
                                                   float* __restrict__ op) {
    float pv[L_];
    float mx = bias[0];
#pragma unroll
    for (int l = 1; l < L_; ++l) mx = fmaxf(mx, bias[l]);
    float s = 0.f;
#pragma unroll
    for (int l = 0; l < L_; ++l) { pv[l] = expf(bias[l] - mx); s += pv[l]; }
    float inv = 1.f / s;
#pragma unroll
    for (int l = 0; l < L_; ++l) op[l] = pv[l] * inv;
}

// ---- Kernel B: coalesced streaming + depth-3 register pipeline ----
// Block 256 thr (4 waves), 64 dense rows. hl=lane&15 spans h (16 lanes x
// float4 = 256B run per row per instr); g=lane>>4 picks row; 4 row-slots/lane.
// W (36KB) in LDS once; 9x broadcast ds_read_b128/iter (2-way alias = free).
// Depth-3 ring buffer keeps 12 loads (3KB/wave) outstanding through compute.
__global__ __launch_bounds__(256, 2) void gemm_kernel(
    const float* __restrict__ seq, const float* __restrict__ W,
    const float* __restrict__ bias, const int* __restrict__ ws_src,
    const int* __restrict__ ws_nv, float* __restrict__ out) {
    __shared__ __align__(16) float Wl[H_ * L_];  // 36,864 B
    __shared__ int offs[B_ + 1];
    __shared__ int srow[RPB];    // absolute source row, -1 = pad
    __shared__ int orow_s[RPB];  // absolute output row

    const int lane = threadIdx.x & 63;
    const int wv = __builtin_amdgcn_readfirstlane(threadIdx.x >> 6);

    // 128-wide exclusive prefix of ws_nv -> offs[0..128] (wave 0)
    if (threadIdx.x < 64) {
        int s0 = ws_nv[lane];
        int s1 = ws_nv[64 + lane];
#pragma unroll
        for (int d = 1; d < 64; d <<= 1) {
            int t0 = __shfl_up(s0, d, 64);
            int t1 = __shfl_up(s1, d, 64);
            if (lane >= d) { s0 += t0; s1 += t1; }
        }
        int tot0 = __shfl(s0, 63, 64);
        offs[1 + lane] = s0;
        offs[65 + lane] = tot0 + s1;
        if (lane == 0) offs[0] = 0;
    }
    __syncthreads();

    const int total = offs[B_];
    const int G0 = blockIdx.x * RPB;
    const bool anyValid = G0 < total;  // block-uniform

    // ---- mapping for this block's 64 rows (thread t -> row t) ----
    if (threadIdx.x < RPB) {
        const int G = G0 + threadIdx.x;
        int orow, srcabs;
        if (G < total) {
            int lo = 0, hi = B_;
            while (hi - lo > 1) {
                int mid = (lo + hi) >> 1;
                if (offs[mid] <= G) lo = mid; else hi = mid;
            }
            int j = G - offs[lo];
            orow = lo * S_ + j;
            srcabs = lo * S_ + ws_src[orow];
        } else {
            int P = G - total;
            int lo = 0, hi = B_;
            while (hi - lo > 1) {
                int mid = (lo + hi) >> 1;
                if (mid * S_ - offs[mid] <= P) lo = mid; else hi = mid;
            }
            int nv = offs[lo + 1] - offs[lo];
            int j = nv + (P - (lo * S_ - offs[lo]));
            orow = lo * S_ + j;
            srcabs = -1;
        }
        srow[threadIdx.x] = srcabs;
        orow_s[threadIdx.x] = orow;
    }

    // ---- cooperative W -> LDS (skip for all-pad blocks) ----
    if (anyValid) {
        const float4* Wg = (const float4*)W;
        float4* Wd = (float4*)Wl;
#pragma unroll
        for (int k = 0; k < 9; ++k)  // 2304 float4s = 9 * 256
            Wd[k * 256 + threadIdx.x] = Wg[k * 256 + threadIdx.x];
    }
    __syncthreads();

    if (!anyValid) {  // all-pad block: bias softmax only, no W/seq reads
        if (threadIdx.x < RPB)
            bias_softmax_store(bias, out + (size_t)orow_s[threadIdx.x] * L_);
        return;
    }

    const int hl = lane & 15;
    const int g = lane >> 4;

    // this lane's 4 source rows (pad -> clamp to row 0, result overridden)
    const float* xb[4];
#pragma unroll
    for (int s = 0; s < 4; ++s) {
        int rw = 16 * wv + 4 * s + g;
        int sa = srow[rw];
        xb[s] = seq + (size_t)(sa < 0 ? 0 : sa) * H_ + 4 * hl;
    }

    float acc[4][L_];
#pragma unroll
    for (int s = 0; s < 4; ++s)
#pragma unroll
        for (int l = 0; l < L_; ++l) acc[s][l] = 0.f;

    // ---- depth-3 software pipeline over 16 h-iterations ----
    // buf[p][s]: float4 for row-slot s, iteration (rotating). Fully unrolled
    // so all indices are compile-time (registers, not scratch).
    float4 buf[3][4];
#pragma unroll
    for (int p = 0; p < 3; ++p)
#pragma unroll
        for (int s = 0; s < 4; ++s)
            buf[p][s] = *(const float4*)(xb[s] + 64 * p);

#pragma unroll
    for (int it = 0; it < 16; ++it) {
        const int slot = it % 3;
        // copy current out of the ring (register renaming under full unroll)
        float4 xv0 = buf[slot][0];
        float4 xv1 = buf[slot][1];
        float4 xv2 = buf[slot][2];
        float4 xv3 = buf[slot][3];
        // immediately refill the slot with iteration it+3 (stays in flight
        // through this iteration's compute)
        if (it + 3 < 16) {
#pragma unroll
            for (int s = 0; s < 4; ++s)
                buf[slot][s] = *(const float4*)(xb[s] + 64 * (it + 3));
        }
        const float* wf = Wl + 36 * hl + 576 * it;
        float wr[36];
#pragma unroll
        for (int j = 0; j < 9; ++j)
            *(float4*)&wr[4 * j] = *(const float4*)(wf + 4 * j);
        float xk0[4] = {xv0.x, xv0.y, xv0.z, xv0.w};
        float xk1[4] = {xv1.x, xv1.y, xv1.z, xv1.w};
        float xk2[4] = {xv2.x, xv2.y, xv2.z, xv2.w};
        float xk3[4] = {xv3.x, xv3.y, xv3.z, xv3.w};
#pragma unroll
        for (int k = 0; k < 4; ++k)
#pragma unroll
            for (int l = 0; l < L_; ++l) {
                float w = wr[9 * k + l];
                acc[0][l] = fmaf(xk0[k], w, acc[0][l]);
                acc[1][l] = fmaf(xk1[k], w, acc[1][l]);
                acc[2][l] = fmaf(xk2[k], w, acc[2][l]);
                acc[3][l] = fmaf(xk3[k], w, acc[3][l]);
            }
    }

    // ---- butterfly reduce over the 16 h-lanes (register-only) ----
#pragma unroll
    for (int m = 1; m < 16; m <<= 1)
#pragma unroll
        for (int s = 0; s < 4; ++s)
#pragma unroll
            for (int l = 0; l < L_; ++l)
                acc[s][l] += __shfl_xor(acc[s][l], m, 16);

    // ---- write: lane with hl<4 writes row 16*wv + 4*hl + g ----
    if (hl < 4) {
        float v[L_];
#pragma unroll
        for (int s = 0; s < 4; ++s)  // static-index select acc[hl]
            if (hl == s) {
#pragma unroll
                for (int l = 0; l < L_; ++l) v[l] = acc[s][l];
            }
        int rw = 16 * wv + 4 * hl + g;
        float* op = out + (size_t)orow_s[rw] * L_;
        if (srow[rw] < 0) {
            bias_softmax_store(bias, op);
        } else {
#pragma unroll
            for (int l = 0; l < L_; ++l) v[l] += bias[l];
            float mx = v[0];
#pragma unroll
            for (int l = 1; l < L_; ++l) mx = fmaxf(mx, v[l]);
            float s = 0.f;
#pragma unroll
            for (int l = 0; l < L_; ++l) {
                v[l] = expf(v[l] - mx);
                s += v[l];
            }
            float inv = 1.f / s;
#pragma unroll
            for (int l = 0; l < L_; ++l) op[l] = v[l] * inv;
        }
    }
}

extern "C" void kernel_launch(void* const* d_in, const int* in_sizes, int n_in,
                              void* d_out, int out_size, void* d_ws, size_t ws_size,
                              hipStream_t stream) {
    const float* seq = (const float*)d_in[0];   // [B,S,H] f32
    const float* W = (const float*)d_in[1];     // [H,L] f32
    const float* bias = (const float*)d_in[2];  // [L] f32
    const int* valid = (const int*)d_in[3];     // [B,S] i32
    float* out = (float*)d_out;                 // [B,S,L] f32

    int* ws_src = (int*)d_ws;        // [128*512] within-batch source indices
    int* ws_nv = ws_src + B_ * S_;   // [128] valid counts

    prep_kernel<<<dim3(B_), dim3(64), 0, stream>>>(valid, ws_src, ws_nv);
    gemm_kernel<<<dim3(B_ * S_ / RPB), dim3(256), 0, stream>>>(seq, W, bias,
                                                               ws_src, ws_nv, out);
}